// Round 9
// baseline (157.358 us; speedup 1.0000x reference)
//
#include <hip/hip_runtime.h>
#include <math.h>

// flash-decode, GQA paged KV. R=4, B=16, Hq=32, Hk=8 (G=4), D=128, P=8192,
// PAGE=1, M=2048.
// Storage (confirmed round 7): q/k_cache/v_cache are FLOAT32 on device
// (harness up-converts the fp16 reference tensors); lens/bt int32; out f32.
//
// Round 9: ILP + issue-rate. 16 tokens/wave-iter (8x32B loads in flight),
// slot-local online softmax (zero shfls in the softmax path; 4 independent
// 4-deep shfl chains for the dots), int4 page-table loads, slot merge once
// in the epilogue. Split-KV S=16 as in round 8.

typedef float f32x4 __attribute__((ext_vector_type(4)));

#define R_ 4
#define B_ 16
#define HQ_ 32
#define HK_ 8
#define G_ 4
#define D_ 128
#define P_ 8192
#define M_ 2048
#define SCALE_F 0.08838834764831845f

__device__ __forceinline__ void load8f(const float* p, float o[8]) {
  f32x4 a = *(const f32x4*)p;
  f32x4 b = *(const f32x4*)(p + 4);
#pragma unroll
  for (int j = 0; j < 4; ++j) { o[j] = a[j]; o[4 + j] = b[j]; }
}

__device__ __forceinline__ int clampP(int p) {
  return p < 0 ? 0 : (p >= P_ ? P_ - 1 : p);
}

// ---------------- kernel 1: per-(r,b,hk,split) partials ----------------
__global__ __launch_bounds__(256) void fd_partial(
    const float* __restrict__ q, const float* __restrict__ kc,
    const float* __restrict__ vc, const int* __restrict__ lens,
    const int* __restrict__ bt, float* __restrict__ ws_m,
    float* __restrict__ ws_l, float* __restrict__ ws_o, int S) {
  const int idx = blockIdx.x;
  const int s = idx % S;
  const int hk = (idx / S) % HK_;
  const int b = (idx / (S * HK_)) % B_;
  const int r = idx / (S * HK_ * B_);

  const int lane = threadIdx.x & 63;
  const int g = threadIdx.x >> 6;  // wave id == GQA sub-head
  const int tg = lane >> 4;        // slot 0..3 (4 tokens each per iter)
  const int ds = (lane & 15) * 8;  // dim slice [ds, ds+8)

  float qf[8];
  load8f(q + (size_t)(b * HQ_ + hk * G_ + g) * D_ + ds, qf);

  int kvlen = lens[r * B_ + b];
  if (kvlen < 0) kvlen = 0;
  if (kvlen > M_) kvlen = M_;
  // chunk aligned to 16 so int4 page loads stay aligned and in [0, M)
  const int chunk = (((kvlen + S - 1) / S) + 15) & ~15;
  const int t0 = s * chunk;
  int t1 = t0 + chunk;
  if (t1 > kvlen) t1 = kvlen;

  const int* btrow = bt + (r * B_ + b) * M_;
  const float* kb = kc + (size_t)r * P_ * HK_ * D_ + (size_t)hk * D_ + ds;
  const float* vb = vc + (size_t)r * P_ * HK_ * D_ + (size_t)hk * D_ + ds;

  // slot-local online softmax state
  float m = -INFINITY, l = 0.f, acc[8];
#pragma unroll
  for (int j = 0; j < 8; ++j) acc[j] = 0.f;

  for (int t = t0; t < t1; t += 16) {
    const int tb_ = t + tg * 4;
    const int4 pg = *(const int4*)(btrow + tb_);
    const bool v0 = tb_ + 0 < t1;
    const bool v1 = tb_ + 1 < t1;
    const bool v2 = tb_ + 2 < t1;
    const bool v3 = tb_ + 3 < t1;
    const size_t o0 = (size_t)clampP(pg.x) * (HK_ * D_);
    const size_t o1 = (size_t)clampP(pg.y) * (HK_ * D_);
    const size_t o2 = (size_t)clampP(pg.z) * (HK_ * D_);
    const size_t o3 = (size_t)clampP(pg.w) * (HK_ * D_);

    float k0[8], k1[8], k2[8], k3[8], w0[8], w1[8], w2[8], w3[8];
    load8f(kb + o0, k0);
    load8f(kb + o1, k1);
    load8f(kb + o2, k2);
    load8f(kb + o3, k3);
    load8f(vb + o0, w0);
    load8f(vb + o1, w1);
    load8f(vb + o2, w2);
    load8f(vb + o3, w3);

    float d0 = 0.f, d1 = 0.f, d2 = 0.f, d3 = 0.f;
#pragma unroll
    for (int j = 0; j < 8; ++j) {
      d0 += qf[j] * k0[j];
      d1 += qf[j] * k1[j];
      d2 += qf[j] * k2[j];
      d3 += qf[j] * k3[j];
    }
    // 4 independent 4-deep shfl-reduce chains over the 16 lanes of the slot
#pragma unroll
    for (int msk = 1; msk <= 8; msk <<= 1) {
      d0 += __shfl_xor(d0, msk);
      d1 += __shfl_xor(d1, msk);
      d2 += __shfl_xor(d2, msk);
      d3 += __shfl_xor(d3, msk);
    }
    const float s0 = v0 ? d0 * SCALE_F : -INFINITY;
    const float s1 = v1 ? d1 * SCALE_F : -INFINITY;
    const float s2 = v2 ? d2 * SCALE_F : -INFINITY;
    const float s3 = v3 ? d3 * SCALE_F : -INFINITY;

    // slot max: scores are replicated within the slot -> lane-local
    const float mt = fmaxf(fmaxf(s0, s1), fmaxf(s2, s3));
    const float mn = fmaxf(m, mt);
    if (mn == -INFINITY) continue;
    const float sc = (m == -INFINITY) ? 0.f : __expf(m - mn);
    const float p0 = __expf(s0 - mn);  // -inf -> 0
    const float p1 = __expf(s1 - mn);
    const float p2 = __expf(s2 - mn);
    const float p3 = __expf(s3 - mn);
    m = mn;
    l = l * sc + (p0 + p1) + (p2 + p3);
#pragma unroll
    for (int j = 0; j < 8; ++j)
      acc[j] = acc[j] * sc + p0 * w0[j] + p1 * w1[j] + p2 * w2[j] + p3 * w3[j];
  }

  // merge the 4 slot states (tree over lane-xor 16, 32)
#pragma unroll
  for (int off = 16; off <= 32; off <<= 1) {
    const float mo = __shfl_xor(m, off);
    const float lo = __shfl_xor(l, off);
    float ao[8];
#pragma unroll
    for (int j = 0; j < 8; ++j) ao[j] = __shfl_xor(acc[j], off);
    const float mn = fmaxf(m, mo);
    const float se = (m == -INFINITY) ? 0.f : __expf(m - mn);
    const float so = (mo == -INFINITY) ? 0.f : __expf(mo - mn);
    l = l * se + lo * so;
#pragma unroll
    for (int j = 0; j < 8; ++j) acc[j] = acc[j] * se + ao[j] * so;
    m = mn;
  }

  const int rec = blockIdx.x;  // == ((r*B+b)*HK + hk)*S + s
  if (lane < 16) {
#pragma unroll
    for (int j = 0; j < 8; ++j)
      ws_o[((size_t)rec * G_ + g) * D_ + ds + j] = acc[j];
    if (lane == 0) {
      ws_m[rec * G_ + g] = m;
      ws_l[rec * G_ + g] = l;
    }
  }
}

// ---------------- kernel 2: LSE-weighted combine over R*S ----------------
__global__ __launch_bounds__(128) void fd_reduce(
    const float* __restrict__ ws_m, const float* __restrict__ ws_l,
    const float* __restrict__ ws_o, float* __restrict__ out, int S) {
  const int row = blockIdx.x;  // (b*HK + hk)*G + g
  const int g = row % G_;
  const int hk = (row / G_) % HK_;
  const int b = row / (G_ * HK_);
  const int d = threadIdx.x;

  float mf = -INFINITY;
  for (int r = 0; r < R_; ++r)
    for (int s = 0; s < S; ++s) {
      int rec = ((r * B_ + b) * HK_ + hk) * S + s;
      mf = fmaxf(mf, ws_m[rec * G_ + g]);
    }
  float of = 0.f, lf = 0.f;
  for (int r = 0; r < R_; ++r)
    for (int s = 0; s < S; ++s) {
      int rec = ((r * B_ + b) * HK_ + hk) * S + s;
      float wm = ws_m[rec * G_ + g];
      if (wm == -INFINITY) continue;
      float wt = __expf(wm - mf);
      of += wt * ws_o[((size_t)rec * G_ + g) * D_ + d];
      lf += wt * ws_l[rec * G_ + g];
    }
  out[(size_t)(b * HQ_ + hk * G_ + g) * D_ + d] = of / lf;
}

// ---------------- fallback: monolithic (tiny workspace) ----------------
__global__ __launch_bounds__(256) void fd_mono(
    const float* __restrict__ q, const float* __restrict__ kc,
    const float* __restrict__ vc, const int* __restrict__ lens,
    const int* __restrict__ bt, float* __restrict__ out) {
  const int hk = blockIdx.x % HK_;
  const int b = blockIdx.x / HK_;
  const int lane = threadIdx.x & 63;
  const int g = threadIdx.x >> 6;
  const int tg = lane >> 4;
  const int ds = (lane & 15) * 8;

  float qf[8];
  load8f(q + (size_t)(b * HQ_ + hk * G_ + g) * D_ + ds, qf);

  float m = -INFINITY, l = 0.f, acc[8];
#pragma unroll
  for (int j = 0; j < 8; ++j) acc[j] = 0.f;

  for (int r = 0; r < R_; ++r) {
    int kvlen = lens[r * B_ + b];
    if (kvlen < 0) kvlen = 0;
    if (kvlen > M_) kvlen = M_;
    const int* btrow = bt + (r * B_ + b) * M_;
    const float* kb = kc + (size_t)r * P_ * HK_ * D_ + (size_t)hk * D_ + ds;
    const float* vb = vc + (size_t)r * P_ * HK_ * D_ + (size_t)hk * D_ + ds;

    for (int t = 0; t < kvlen; t += 4) {
      const int ta = t + tg;
      const bool va = ta < kvlen;
      const int pga = clampP(btrow[va ? ta : 0]);
      const size_t offa = (size_t)pga * (HK_ * D_);
      float ka[8], wa[8];
      load8f(kb + offa, ka);
      load8f(vb + offa, wa);

      float da = 0.f;
#pragma unroll
      for (int j = 0; j < 8; ++j) da += qf[j] * ka[j];
#pragma unroll
      for (int msk = 1; msk <= 8; msk <<= 1) da += __shfl_xor(da, msk);

      const float sa = va ? da * SCALE_F : -INFINITY;
      const float mn = fmaxf(m, sa);
      if (mn == -INFINITY) continue;
      const float sc = (m == -INFINITY) ? 0.f : __expf(m - mn);
      const float pa = __expf(sa - mn);
      m = mn;
      l = l * sc + pa;
#pragma unroll
      for (int j = 0; j < 8; ++j) acc[j] = acc[j] * sc + pa * wa[j];
    }
  }

#pragma unroll
  for (int off = 16; off <= 32; off <<= 1) {
    const float mo = __shfl_xor(m, off);
    const float lo = __shfl_xor(l, off);
    float ao[8];
#pragma unroll
    for (int j = 0; j < 8; ++j) ao[j] = __shfl_xor(acc[j], off);
    const float mn = fmaxf(m, mo);
    const float se = (m == -INFINITY) ? 0.f : __expf(m - mn);
    const float so = (mo == -INFINITY) ? 0.f : __expf(mo - mn);
    l = l * se + lo * so;
#pragma unroll
    for (int j = 0; j < 8; ++j) acc[j] = acc[j] * se + ao[j] * so;
    m = mn;
  }

  if (lane < 16) {
    float inv = (l > 0.f) ? 1.0f / l : 0.f;
#pragma unroll
    for (int j = 0; j < 8; ++j)
      out[(size_t)(b * HQ_ + hk * G_ + g) * D_ + ds + j] = acc[j] * inv;
  }
}

extern "C" void kernel_launch(void* const* d_in, const int* in_sizes, int n_in,
                              void* d_out, int out_size, void* d_ws,
                              size_t ws_size, hipStream_t stream) {
  const float* q = (const float*)d_in[0];
  const float* kc = (const float*)d_in[1];
  const float* vc = (const float*)d_in[2];
  const int* lens = (const int*)d_in[3];
  const int* bt = (const int*)d_in[4];
  float* out = (float*)d_out;

  auto need = [](int s) {
    return (size_t)R_ * B_ * HK_ * s * (size_t)(2 * G_ + G_ * D_) *
           sizeof(float);
  };
  int S = 16;
  while (S > 1 && need(S) > ws_size) S >>= 1;

  if (need(S) <= ws_size) {
    const int nrec = R_ * B_ * HK_ * S;
    float* ws_m = (float*)d_ws;
    float* ws_l = ws_m + (size_t)nrec * G_;
    float* ws_o = ws_l + (size_t)nrec * G_;
    fd_partial<<<nrec, 256, 0, stream>>>(q, kc, vc, lens, bt, ws_m, ws_l,
                                         ws_o, S);
    fd_reduce<<<B_ * HK_ * G_, 128, 0, stream>>>(ws_m, ws_l, ws_o, out, S);
  } else {
    fd_mono<<<B_ * HK_, 256, 0, stream>>>(q, kc, vc, lens, bt, out);
  }
}